// Round 9
// baseline (782.675 us; speedup 1.0000x reference)
//
#include <hip/hip_runtime.h>

// ---------------------------------------------------------------------------
// NeighborEmbedder on MI355X (gfx950). Round 9: 4 blocks/CU for the GEMM.
//  - gemm_k2: 2 LDS buffers (32 KB, depth-1 prefetch, vmcnt(0) pre-barrier)
//    + __launch_bounds__(256,4) to force <=128 unified VGPR+AGPR.
//  - Everything else identical to R8 (best: 780 us).
// Occupancy history: 2 blk/CU -> MfmaUtil 13% (R7), 3 -> 31% (R6/R8);
// wave-TLP is what hides the per-kt latency, so buy a 4th block.
// ---------------------------------------------------------------------------

typedef unsigned short u16;
typedef u16   u16x8 __attribute__((ext_vector_type(8)));
typedef u16   u16x4 __attribute__((ext_vector_type(4)));
typedef __bf16 bf16x8 __attribute__((ext_vector_type(8)));
typedef __bf16 bf16x4 __attribute__((ext_vector_type(4)));
typedef float f32x4 __attribute__((ext_vector_type(4)));

static __device__ __forceinline__ u16 f2bf(float f) {
  union { float f; unsigned u; } v; v.f = f;
  unsigned r = v.u + 0x7FFFu + ((v.u >> 16) & 1u);   // RNE
  return (u16)(r >> 16);
}
static __device__ __forceinline__ float bf2f(u16 u) {
  union { unsigned u; float f; } v; v.u = ((unsigned)u) << 16;
  return v.f;
}

// async global->LDS, 16B per lane. LDS dest wave-uniform base + lane*16.
static __device__ __forceinline__ void gld16(const void* g, void* l) {
  __builtin_amdgcn_global_load_lds(
      (__attribute__((address_space(1))) unsigned int*)(size_t)g,
      (__attribute__((address_space(3))) unsigned int*)(unsigned)(size_t)l,
      16, 0, 0);
}

// bijective XCD-chunked swizzle (m204)
static __device__ __forceinline__ int xcd_swz(int bid, int nwg) {
  int q = nwg >> 3, r = nwg & 7;
  int xcd = bid & 7, sub = bid >> 3;
  return (xcd < r ? xcd * (q + 1) : r * (q + 1) + (xcd - r) * q) + sub;
}

#define BAR   __builtin_amdgcn_s_barrier()
#define VM0   asm volatile("s_waitcnt vmcnt(0)" ::: "memory")
#define VM2   asm volatile("s_waitcnt vmcnt(2)" ::: "memory")
#define LGKM0 asm volatile("s_waitcnt lgkmcnt(0)" ::: "memory")

// ---------------------------------------------------------------------------
// gemm_k2: out[M,N](bf16) = A[M,K] @ W[N,K]^T + bias (+pos/+res/gelu)
// 128x128 tile, BK=32, 256 threads = 4 waves (2M x 2N), each wave 64x64 out.
// 2 LDS buffers (32 KB), depth-1 prefetch: stage kt+1 at iter top, MFMA on
// cur, vmcnt(0) before the single barrier. LDS swizzle: granule g at row r
// stored at g ^ ((r>>1)&3), both sides (conflict-free, verified R6).
// A_F32: A staged via reg load + hw bf16 cvt + swizzled ds_write.
// Requires M%128==0, N%128==0, K%32==0, K>=64.
// ---------------------------------------------------------------------------
template<bool A_F32, bool HAS_POS, bool HAS_RES, bool HAS_GELU>
__global__ __launch_bounds__(256, 4) void gemm_k2(
    const void* Av, int lda,
    const u16* __restrict__ W,
    const float* __restrict__ bias,
    const float* __restrict__ pos,
    const u16* res, int res_stride,
    u16* out,
    int M, int N, int K, int nbx)
{
  __shared__ u16 As[2][4096];   // 2 x 128x32 bf16 = 2 x 8 KB
  __shared__ u16 Bs[2][4096];

  const int t    = threadIdx.x;
  const int lane = t & 63, wv = t >> 6;
  const int swz  = xcd_swz(blockIdx.x, gridDim.x);
  const int bm   = (swz / nbx) * 128, bn = (swz % nbx) * 128;
  const int wr   = wv >> 1, wc = wv & 1;

  const int srow = lane >> 2;
  const int skk  = (((lane & 3) ^ ((lane >> 3) & 3)) << 3);  // pre-swz src col
  const int lr = lane & 15;
  const int rg = (((lane >> 4) ^ ((lr >> 1) & 3)) << 3);     // swz read col

  f32x4 acc[4][4] = {};
  float4 areg[4];               // A_F32 staging regs (only in that variant)

  auto stage = [&](int buf, int kt) {          // bf16 A+B: 4 gld16 per wave
    const u16* A = (const u16*)Av;
    #pragma unroll
    for (int c = 0; c < 2; ++c) {
      int rr = (wv + 4 * c) * 16 + srow;
      gld16(A + (size_t)(bm + rr) * lda + kt * 32 + skk, &As[buf][(wv + 4 * c) * 512]);
      gld16(W + (size_t)(bn + rr) * K   + kt * 32 + skk, &Bs[buf][(wv + 4 * c) * 512]);
    }
  };
  auto stageB = [&](int buf, int kt) {         // 2 gld16 per wave
    #pragma unroll
    for (int c = 0; c < 2; ++c) {
      int rr = (wv + 4 * c) * 16 + srow;
      gld16(W + (size_t)(bn + rr) * K + kt * 32 + skk, &Bs[buf][(wv + 4 * c) * 512]);
    }
  };
  auto loadAf32 = [&](int kt) {                // 4 float4 per thread (128x32)
    const float* A = (const float*)Av;
    #pragma unroll
    for (int i = 0; i < 4; ++i) {
      int idx = i * 256 + t, r = idx >> 3, c4 = (idx & 7) * 4;
      areg[i] = *(const float4*)(A + (size_t)(bm + r) * lda + kt * 32 + c4);
    }
  };
  auto writeAf32 = [&](int buf) {              // cvt + swizzled ds_write
    #pragma unroll
    for (int i = 0; i < 4; ++i) {
      int idx = i * 256 + t, r = idx >> 3, c4 = (idx & 7) * 4;
      int g = (c4 >> 3) ^ ((r >> 1) & 3);
      int off = r * 32 + g * 8 + (c4 & 4);     // u16 units
      bf16x4 h;
      h.x = (__bf16)areg[i].x; h.y = (__bf16)areg[i].y;
      h.z = (__bf16)areg[i].z; h.w = (__bf16)areg[i].w;
      *(u16x4*)&As[buf][off] = *(u16x4*)&h;
    }
  };

  const int nkt = K >> 5;
  // ---- prologue: kt0 -> buf0
  if constexpr (A_F32) {
    loadAf32(0); stageB(0, 0);
    VM2;  writeAf32(0);                 // A0 regs in; B0 may fly
    VM0; LGKM0; BAR;                    // B0 done, ds_writes visible
  } else {
    stage(0, 0);
    VM0; BAR;
  }

  int cur = 0;
  for (int kt = 0; kt < nkt; ++kt) {
    const bool pf = (kt + 1 < nkt);
    if (pf) {
      if constexpr (A_F32) { loadAf32(kt + 1); stageB(cur ^ 1, kt + 1); }
      else                 { stage(cur ^ 1, kt + 1); }
    }

    bf16x8 a[4], b[4];
    #pragma unroll
    for (int m = 0; m < 4; ++m)
      a[m] = *(const bf16x8*)&As[cur][(wr * 64 + m * 16 + lr) * 32 + rg];
    #pragma unroll
    for (int n = 0; n < 4; ++n)
      b[n] = *(const bf16x8*)&Bs[cur][(wc * 64 + n * 16 + lr) * 32 + rg];
    #pragma unroll
    for (int m = 0; m < 4; ++m)
      #pragma unroll
      for (int n = 0; n < 4; ++n)
        acc[m][n] = __builtin_amdgcn_mfma_f32_16x16x32_bf16(a[m], b[n], acc[m][n], 0, 0, 0);

    if (pf) {
      if constexpr (A_F32) { VM2; writeAf32(cur ^ 1); VM0; LGKM0; }
      else                 { VM0; }
    }
    BAR;
    cur ^= 1;
  }

  // epilogue: row=(lane>>4)*4+r (+m*16), col=lane&15 (+n*16)  [m89 layout]
  const int lq = lane >> 4;
  #pragma unroll
  for (int m = 0; m < 4; ++m) {
    #pragma unroll
    for (int n = 0; n < 4; ++n) {
      int col = bn + wc * 64 + n * 16 + lr;
      float bv = bias[col];
      #pragma unroll
      for (int r = 0; r < 4; ++r) {
        int row = bm + wr * 64 + m * 16 + lq * 4 + r;
        float v = acc[m][n][r] + bv;
        if constexpr (HAS_POS) v += pos[(row % 9) * 512 + col];
        if constexpr (HAS_RES) v += bf2f(res[(size_t)row * res_stride + col]);
        if constexpr (HAS_GELU) v = 0.5f * v * (1.f + erff(v * 0.70710678118f));
        out[(size_t)row * N + col] = f2bf(v);
      }
    }
  }
}

// ---------------------------------------------------------------------------
// LayerNorm over rows of 512 (bf16 in). One wave per row, 4 rows per block.
// ---------------------------------------------------------------------------
__global__ __launch_bounds__(256) void ln_k(
    const u16* in,
    const float* __restrict__ g, const float* __restrict__ be,
    u16* out_bf, float* out_f32, int rows)
{
  int wv = threadIdx.x >> 6, lane = threadIdx.x & 63;
  int row = blockIdx.x * 4 + wv;
  if (row >= rows) return;
  const u16* p = in + (size_t)row * 512;
  u16x8 v = *(const u16x8*)&p[lane * 8];
  float x[8], s = 0.f, sq = 0.f;
  #pragma unroll
  for (int j = 0; j < 8; ++j) { x[j] = bf2f(v[j]); s += x[j]; sq += x[j] * x[j]; }
  #pragma unroll
  for (int o = 32; o > 0; o >>= 1) { s += __shfl_xor(s, o, 64); sq += __shfl_xor(sq, o, 64); }
  float mean = s * (1.f / 512.f);
  float var  = sq * (1.f / 512.f) - mean * mean;
  float rs   = rsqrtf(var + 1e-5f);
  float y[8];
  #pragma unroll
  for (int j = 0; j < 8; ++j) {
    int c = lane * 8 + j;
    y[j] = (x[j] - mean) * rs * g[c] + be[c];
  }
  if (out_bf) {
    u16x8 o8;
    #pragma unroll
    for (int j = 0; j < 8; ++j) o8[j] = f2bf(y[j]);
    *(u16x8*)&out_bf[(size_t)row * 512 + lane * 8] = o8;
  }
  if (out_f32) {
    #pragma unroll
    for (int j = 0; j < 8; ++j) out_f32[(size_t)row * 512 + lane * 8 + j] = y[j];
  }
}

// ---------------------------------------------------------------------------
// Self-attention, one block per sample: qkv[9,1536] (q|k|v), H=8, d=64, L=9.
// ---------------------------------------------------------------------------
__global__ __launch_bounds__(256) void sa_attn_k(const u16* __restrict__ qkv,
                                                 u16* __restrict__ out)
{
  __shared__ u16  s_qkv[9 * 1536];
  __shared__ float s_sc[8][81];
  const int s = blockIdx.x, t = threadIdx.x;
  const u16* src = qkv + (size_t)s * 9 * 1536;
  for (int i = t; i < (9 * 1536) / 8; i += 256)
    *(u16x8*)&s_qkv[i * 8] = *(const u16x8*)&src[i * 8];
  __syncthreads();

  const int h = t >> 5, sl = t & 31;
  for (int p = sl; p < 81; p += 32) {
    int qi = p / 9, ki = p % 9;
    const u16* qp = &s_qkv[qi * 1536 + h * 64];
    const u16* kp = &s_qkv[ki * 1536 + 512 + h * 64];
    float d = 0.f;
    #pragma unroll
    for (int e8 = 0; e8 < 8; ++e8) {
      u16x8 qv = *(const u16x8*)&qp[e8 * 8];
      u16x8 kv = *(const u16x8*)&kp[e8 * 8];
      #pragma unroll
      for (int j = 0; j < 8; ++j) d += bf2f(qv[j]) * bf2f(kv[j]);
    }
    s_sc[h][p] = d * 0.125f;
  }
  __syncthreads();

  if (t < 72) {
    int hh = t / 9, qi = t % 9;
    float* sc = &s_sc[hh][qi * 9];
    float mx = sc[0];
    #pragma unroll
    for (int i = 1; i < 9; ++i) mx = fmaxf(mx, sc[i]);
    float e[9], sum = 0.f;
    #pragma unroll
    for (int i = 0; i < 9; ++i) { e[i] = __expf(sc[i] - mx); sum += e[i]; }
    float inv = 1.f / sum;
    #pragma unroll
    for (int i = 0; i < 9; ++i) sc[i] = e[i] * inv;
  }
  __syncthreads();

  for (int gidx = sl; gidx < 72; gidx += 32) {
    int qi = gidx >> 3, dg = gidx & 7;
    float a[8] = {};
    #pragma unroll
    for (int ki = 0; ki < 9; ++ki) {
      float pr = s_sc[h][qi * 9 + ki];
      u16x8 vv = *(const u16x8*)&s_qkv[ki * 1536 + 1024 + h * 64 + dg * 8];
      #pragma unroll
      for (int j = 0; j < 8; ++j) a[j] += pr * bf2f(vv[j]);
    }
    u16x8 o8;
    #pragma unroll
    for (int j = 0; j < 8; ++j) o8[j] = f2bf(a[j]);
    *(u16x8*)&out[((size_t)s * 9 + qi) * 512 + h * 64 + dg * 8] = o8;
  }
}

// ---------------------------------------------------------------------------
// Cross-attention, one block per sample: q[512], kv[9,1024] (k|v).
// ---------------------------------------------------------------------------
__global__ __launch_bounds__(256) void ca_attn_k(const u16* __restrict__ q,
                                                 const u16* __restrict__ kv,
                                                 u16* __restrict__ out)
{
  __shared__ u16  s_q[512];
  __shared__ u16  s_kv[9 * 1024];
  __shared__ float s_sc[8][9];
  const int s = blockIdx.x, t = threadIdx.x;
  if (t < 64) *(u16x8*)&s_q[t * 8] = *(const u16x8*)&q[(size_t)s * 512 + t * 8];
  for (int i = t; i < (9 * 1024) / 8; i += 256)
    *(u16x8*)&s_kv[i * 8] = *(const u16x8*)&kv[(size_t)s * 9 * 1024 + i * 8];
  __syncthreads();

  if (t < 72) {
    int h = t / 9, ki = t % 9;
    const u16* qp = &s_q[h * 64];
    const u16* kp = &s_kv[ki * 1024 + h * 64];
    float d = 0.f;
    #pragma unroll
    for (int e8 = 0; e8 < 8; ++e8) {
      u16x8 qv = *(const u16x8*)&qp[e8 * 8];
      u16x8 kvv = *(const u16x8*)&kp[e8 * 8];
      #pragma unroll
      for (int j = 0; j < 8; ++j) d += bf2f(qv[j]) * bf2f(kvv[j]);
    }
    s_sc[h][ki] = d * 0.125f;
  }
  __syncthreads();

  if (t < 8) {
    float* sc = s_sc[t];
    float mx = sc[0];
    #pragma unroll
    for (int i = 1; i < 9; ++i) mx = fmaxf(mx, sc[i]);
    float e[9], sum = 0.f;
    #pragma unroll
    for (int i = 0; i < 9; ++i) { e[i] = __expf(sc[i] - mx); sum += e[i]; }
    float inv = 1.f / sum;
    #pragma unroll
    for (int i = 0; i < 9; ++i) sc[i] = e[i] * inv;
  }
  __syncthreads();

  if (t < 64) {
    int h = t >> 3, dg = t & 7;
    float a[8] = {};
    #pragma unroll
    for (int ki = 0; ki < 9; ++ki) {
      float pr = s_sc[h][ki];
      u16x8 vv = *(const u16x8*)&s_kv[ki * 1024 + 512 + h * 64 + dg * 8];
      #pragma unroll
      for (int j = 0; j < 8; ++j) a[j] += pr * bf2f(vv[j]);
    }
    u16x8 o8;
    #pragma unroll
    for (int j = 0; j < 8; ++j) o8[j] = f2bf(a[j]);
    *(u16x8*)&out[(size_t)s * 512 + h * 64 + dg * 8] = o8;
  }
}

// ---------------------------------------------------------------------------
// Fused weight conversion: all 7 f32 weight tensors -> contiguous bf16 region.
// Block-range -> segment mapping is uniform scalar (no divergence).
// 1024 elements per block; grid = 4480 blocks exactly.
// ---------------------------------------------------------------------------
__global__ __launch_bounds__(256) void wcvt_k(
    const float* s0, const float* s1, const float* s2, const float* s3,
    const float* s4, const float* s5, const float* s6, u16* dst)
{
  int b = blockIdx.x;
  const float* sp; long base, segStart;
  if      (b < 384)  { sp = s0; base = 0;       segStart = 0;    }
  else if (b < 1152) { sp = s1; base = 393216;  segStart = 384;  }
  else if (b < 1408) { sp = s2; base = 1179648; segStart = 1152; }
  else if (b < 2176) { sp = s3; base = 1441792; segStart = 1408; }
  else if (b < 2432) { sp = s4; base = 2228224; segStart = 2176; }
  else if (b < 3456) { sp = s5; base = 2490368; segStart = 2432; }
  else               { sp = s6; base = 3538944; segStart = 3456; }
  long loc = ((long)b - segStart) * 1024 + (long)threadIdx.x * 4;
  float4 f = *(const float4*)(sp + loc);
  u16x4 o; o.x = f2bf(f.x); o.y = f2bf(f.y); o.z = f2bf(f.z); o.w = f2bf(f.w);
  *(u16x4*)&dst[base + loc] = o;
}

// ---------------------------------------------------------------------------
// Host launcher
// ---------------------------------------------------------------------------
extern "C" void kernel_launch(void* const* d_in, const int* in_sizes, int n_in,
                              void* d_out, int out_size, void* d_ws, size_t ws_size,
                              hipStream_t stream)
{
  const float* patches  = (const float*)d_in[0];
  const float* w_pe     = (const float*)d_in[1];
  const float* b_pe     = (const float*)d_in[2];
  const float* pos      = (const float*)d_in[3];
  const float* sa_in_w  = (const float*)d_in[4];
  const float* sa_in_b  = (const float*)d_in[5];
  const float* sa_out_w = (const float*)d_in[6];
  const float* sa_out_b = (const float*)d_in[7];
  const float* g1       = (const float*)d_in[8];
  const float* beta1    = (const float*)d_in[9];
  const float* ca_in_w  = (const float*)d_in[10];
  const float* ca_in_b  = (const float*)d_in[11];
  const float* ca_out_w = (const float*)d_in[12];
  const float* ca_out_b = (const float*)d_in[13];
  const float* g2       = (const float*)d_in[14];
  const float* beta2    = (const float*)d_in[15];
  const float* w1       = (const float*)d_in[16];
  const float* b1       = (const float*)d_in[17];
  const float* w2       = (const float*)d_in[18];
  const float* b2       = (const float*)d_in[19];
  const float* g3       = (const float*)d_in[20];
  const float* beta3    = (const float*)d_in[21];
  float* out = (float*)d_out;

  // workspace layout (bytes)
  char* base = (char*)d_ws;
  u16* wbf        = (u16*)base;
  u16* w_pe_bf    = wbf;
  u16* sa_in_bf   = wbf + 393216;
  u16* sa_out_bf  = wbf + 1179648;
  u16* ca_in_bf   = wbf + 1441792;
  u16* ca_out_bf  = wbf + 2228224;
  u16* w1_bf      = wbf + 2490368;
  u16* w2_bf      = wbf + 3538944;
  u16* x_bf  = (u16*)(base + 9175040ull);     // [73728,512]
  u16* qkv   = (u16*)(base + 84672512ull);    // [73728,1536]; also CA kv
  u16* sattn = (u16*)(base + 311164928ull);   // [73728,512]
  u16* q_bf  = (u16*)(base + 386662400ull);   // [8192,512]
  u16* cattn = (u16*)(base + 395051008ull);   // [8192,512]
  u16* csum  = (u16*)(base + 403439616ull);   // [8192,512]
  u16* h_bf  = (u16*)(base + 411828224ull);   // [8192,2048]
  u16* osum  = (u16*)(base + 445382656ull);   // [8192,512]

  // all weights -> bf16 in one kernel (4480 blocks x 1024 elems)
  wcvt_k<<<4480, 256, 0, stream>>>(w_pe, sa_in_w, sa_out_w, ca_in_w,
                                   ca_out_w, w1, w2, wbf);

  // 1. patch embed + bias + pos_embed -> x_bf  (f32 A fused in staging)
  gemm_k2<true, true, false, false><<<2304, 256, 0, stream>>>(
      patches, 768, w_pe_bf, b_pe, pos, nullptr, 0, x_bf, 73728, 512, 768, 4);
  // 2. SA qkv
  gemm_k2<false, false, false, false><<<6912, 256, 0, stream>>>(
      x_bf, 512, sa_in_bf, sa_in_b, nullptr, nullptr, 0, qkv, 73728, 1536, 512, 12);
  // 3. SA attention
  sa_attn_k<<<8192, 256, 0, stream>>>(qkv, sattn);
  // 4. SA out proj + residual(x) -> x_bf (elementwise in-place)
  gemm_k2<false, false, true, false><<<2304, 256, 0, stream>>>(
      sattn, 512, sa_out_bf, sa_out_b, nullptr, x_bf, 512, x_bf, 73728, 512, 512, 4);
  // 5. LN1 (in place)
  ln_k<<<73728 / 4, 256, 0, stream>>>(x_bf, g1, beta1, x_bf, nullptr, 73728);
  // 6. CA q from center token (row stride 9*512, offset 4*512)
  gemm_k2<false, false, false, false><<<256, 256, 0, stream>>>(
      x_bf + 2048, 4608, ca_in_bf, ca_in_b, nullptr, nullptr, 0, q_bf, 8192, 512, 512, 4);
  // 7. CA kv (wk|wv = ca_in_w rows 512..1535)
  gemm_k2<false, false, false, false><<<4608, 256, 0, stream>>>(
      x_bf, 512, ca_in_bf + 262144, ca_in_b + 512, nullptr, nullptr, 0, qkv, 73728, 1024, 512, 8);
  // 8. CA attention
  ca_attn_k<<<8192, 256, 0, stream>>>(q_bf, qkv, cattn);
  // 9. CA out proj + residual(cq) -> csum
  gemm_k2<false, false, true, false><<<256, 256, 0, stream>>>(
      cattn, 512, ca_out_bf, ca_out_b, nullptr, x_bf + 2048, 4608, csum, 8192, 512, 512, 4);
  // 10. LN2 (in place) -> c
  ln_k<<<8192 / 4, 256, 0, stream>>>(csum, g2, beta2, csum, nullptr, 8192);
  // 11. FFN1 + exact GELU -> h_bf
  gemm_k2<false, false, false, true><<<1024, 256, 0, stream>>>(
      csum, 512, w1_bf, b1, nullptr, nullptr, 0, h_bf, 8192, 2048, 512, 16);
  // 12. FFN2 + residual(c) -> osum
  gemm_k2<false, false, true, false><<<256, 256, 0, stream>>>(
      h_bf, 2048, w2_bf, b2, nullptr, csum, 512, osum, 8192, 512, 2048, 4);
  // 13. LN3 -> d_out (f32)
  ln_k<<<8192 / 4, 256, 0, stream>>>(osum, g3, beta3, nullptr, out, 8192);
}

// Round 10
// 768.391 us; speedup vs baseline: 1.0186x; 1.0186x over previous
//
#include <hip/hip_runtime.h>

// ---------------------------------------------------------------------------
// NeighborEmbedder on MI355X (gfx950). Round 10: arithmetic-intensity round.
// Evidence (R5-R9): every 128x128 schedule variant plateaus at ~698 TF =
// 64 FLOP/B x ~10.5 TB/s cache-side supply. gemm_t raises intensity:
// BM=256 x BN=128, 512 thr = 8 waves (4M x 2N), per-wave 64x64 identical to
// the proven R9 schedule; 2 blocks/CU x 8 waves = same 16 waves/CU TLP.
// PE (A_F32 fused cvt), CAq, CAproj, FFN2 keep gemm_k2 (M=8192 or f32-A).
// ---------------------------------------------------------------------------

typedef unsigned short u16;
typedef u16   u16x8 __attribute__((ext_vector_type(8)));
typedef u16   u16x4 __attribute__((ext_vector_type(4)));
typedef __bf16 bf16x8 __attribute__((ext_vector_type(8)));
typedef __bf16 bf16x4 __attribute__((ext_vector_type(4)));
typedef float f32x4 __attribute__((ext_vector_type(4)));

static __device__ __forceinline__ u16 f2bf(float f) {
  union { float f; unsigned u; } v; v.f = f;
  unsigned r = v.u + 0x7FFFu + ((v.u >> 16) & 1u);   // RNE
  return (u16)(r >> 16);
}
static __device__ __forceinline__ float bf2f(u16 u) {
  union { unsigned u; float f; } v; v.u = ((unsigned)u) << 16;
  return v.f;
}

// async global->LDS, 16B per lane. LDS dest wave-uniform base + lane*16.
static __device__ __forceinline__ void gld16(const void* g, void* l) {
  __builtin_amdgcn_global_load_lds(
      (__attribute__((address_space(1))) unsigned int*)(size_t)g,
      (__attribute__((address_space(3))) unsigned int*)(unsigned)(size_t)l,
      16, 0, 0);
}

// bijective XCD-chunked swizzle (m204)
static __device__ __forceinline__ int xcd_swz(int bid, int nwg) {
  int q = nwg >> 3, r = nwg & 7;
  int xcd = bid & 7, sub = bid >> 3;
  return (xcd < r ? xcd * (q + 1) : r * (q + 1) + (xcd - r) * q) + sub;
}

#define BAR   __builtin_amdgcn_s_barrier()
#define VM0   asm volatile("s_waitcnt vmcnt(0)" ::: "memory")
#define VM2   asm volatile("s_waitcnt vmcnt(2)" ::: "memory")
#define LGKM0 asm volatile("s_waitcnt lgkmcnt(0)" ::: "memory")

// ---------------------------------------------------------------------------
// gemm_t: out[M,N](bf16) = A[M,K](bf16) @ W[N,K]^T + bias (+res/gelu)
// 256x128 tile, BK=32, 512 threads = 8 waves (4M x 2N), per-wave 64x64.
// 2 LDS buffers (48 KB), depth-1 prefetch, vmcnt(0) pre-barrier, one barrier
// per kt (R9-proven schedule). R6 swizzle: granule g at row r at g^((r>>1)&3).
// Intensity: 24 KB fetched per 2.1 MFLOP block-kt = 85 FLOP/B (vs 64 at 128^2).
// Requires M%256==0, N%128==0, K%32==0, K>=64.
// ---------------------------------------------------------------------------
template<bool HAS_RES, bool HAS_GELU>
__global__ __launch_bounds__(512, 4) void gemm_t(
    const u16* __restrict__ A, int lda,
    const u16* __restrict__ W,
    const float* __restrict__ bias,
    const u16* res, int res_stride,
    u16* out,
    int M, int N, int K, int nbx)
{
  __shared__ u16 As[2][8192];   // 256x32 bf16 = 16 KB
  __shared__ u16 Bs[2][4096];   // 128x32 bf16 =  8 KB

  const int t    = threadIdx.x;
  const int lane = t & 63, wv = t >> 6;        // 8 waves
  const int swz  = xcd_swz(blockIdx.x, gridDim.x);
  const int bm   = (swz / nbx) * 256, bn = (swz % nbx) * 128;
  const int wr   = wv >> 1, wc = wv & 1;       // 4(M) x 2(N) wave grid

  const int srow = lane >> 2;
  const int skk  = (((lane & 3) ^ ((lane >> 3) & 3)) << 3);  // pre-swz src col
  const int lr = lane & 15;
  const int rg = (((lane >> 4) ^ ((lr >> 1) & 3)) << 3);     // swz read col

  f32x4 acc[4][4] = {};

  auto stage = [&](int buf, int kt) {          // 3 gld16 per wave
    #pragma unroll
    for (int c = 0; c < 2; ++c) {              // A rows [wv*32, wv*32+32)
      int rr = wv * 32 + c * 16 + srow;
      gld16(A + (size_t)(bm + rr) * lda + kt * 32 + skk,
            &As[buf][(wv * 2 + c) * 512]);
    }
    int rb = wv * 16 + srow;                   // B rows [wv*16, wv*16+16)
    gld16(W + (size_t)(bn + rb) * K + kt * 32 + skk, &Bs[buf][wv * 512]);
  };

  const int nkt = K >> 5;
  stage(0, 0);
  VM0; BAR;

  int cur = 0;
  for (int kt = 0; kt < nkt; ++kt) {
    const bool pf = (kt + 1 < nkt);
    if (pf) stage(cur ^ 1, kt + 1);

    bf16x8 a[4], b[4];
    #pragma unroll
    for (int m = 0; m < 4; ++m)
      a[m] = *(const bf16x8*)&As[cur][(wr * 64 + m * 16 + lr) * 32 + rg];
    #pragma unroll
    for (int n = 0; n < 4; ++n)
      b[n] = *(const bf16x8*)&Bs[cur][(wc * 64 + n * 16 + lr) * 32 + rg];
    #pragma unroll
    for (int m = 0; m < 4; ++m)
      #pragma unroll
      for (int n = 0; n < 4; ++n)
        acc[m][n] = __builtin_amdgcn_mfma_f32_16x16x32_bf16(a[m], b[n], acc[m][n], 0, 0, 0);

    if (pf) VM0;
    BAR;
    cur ^= 1;
  }

  // epilogue: row=(lane>>4)*4+r (+m*16), col=lane&15 (+n*16)  [m89 layout]
  const int lq = lane >> 4;
  #pragma unroll
  for (int m = 0; m < 4; ++m) {
    #pragma unroll
    for (int n = 0; n < 4; ++n) {
      int col = bn + wc * 64 + n * 16 + lr;
      float bv = bias[col];
      #pragma unroll
      for (int r = 0; r < 4; ++r) {
        int row = bm + wr * 64 + m * 16 + lq * 4 + r;
        float v = acc[m][n][r] + bv;
        if constexpr (HAS_RES) v += bf2f(res[(size_t)row * res_stride + col]);
        if constexpr (HAS_GELU) v = 0.5f * v * (1.f + erff(v * 0.70710678118f));
        out[(size_t)row * N + col] = f2bf(v);
      }
    }
  }
}

// ---------------------------------------------------------------------------
// gemm_k2: 128x128 tile (R9, unchanged) for PE(A_F32) and M=8192 GEMMs.
// ---------------------------------------------------------------------------
template<bool A_F32, bool HAS_POS, bool HAS_RES, bool HAS_GELU>
__global__ __launch_bounds__(256, 4) void gemm_k2(
    const void* Av, int lda,
    const u16* __restrict__ W,
    const float* __restrict__ bias,
    const float* __restrict__ pos,
    const u16* res, int res_stride,
    u16* out,
    int M, int N, int K, int nbx)
{
  __shared__ u16 As[2][4096];
  __shared__ u16 Bs[2][4096];

  const int t    = threadIdx.x;
  const int lane = t & 63, wv = t >> 6;
  const int swz  = xcd_swz(blockIdx.x, gridDim.x);
  const int bm   = (swz / nbx) * 128, bn = (swz % nbx) * 128;
  const int wr   = wv >> 1, wc = wv & 1;

  const int srow = lane >> 2;
  const int skk  = (((lane & 3) ^ ((lane >> 3) & 3)) << 3);
  const int lr = lane & 15;
  const int rg = (((lane >> 4) ^ ((lr >> 1) & 3)) << 3);

  f32x4 acc[4][4] = {};
  float4 areg[4];

  auto stage = [&](int buf, int kt) {
    const u16* A = (const u16*)Av;
    #pragma unroll
    for (int c = 0; c < 2; ++c) {
      int rr = (wv + 4 * c) * 16 + srow;
      gld16(A + (size_t)(bm + rr) * lda + kt * 32 + skk, &As[buf][(wv + 4 * c) * 512]);
      gld16(W + (size_t)(bn + rr) * K   + kt * 32 + skk, &Bs[buf][(wv + 4 * c) * 512]);
    }
  };
  auto stageB = [&](int buf, int kt) {
    #pragma unroll
    for (int c = 0; c < 2; ++c) {
      int rr = (wv + 4 * c) * 16 + srow;
      gld16(W + (size_t)(bn + rr) * K + kt * 32 + skk, &Bs[buf][(wv + 4 * c) * 512]);
    }
  };
  auto loadAf32 = [&](int kt) {
    const float* A = (const float*)Av;
    #pragma unroll
    for (int i = 0; i < 4; ++i) {
      int idx = i * 256 + t, r = idx >> 3, c4 = (idx & 7) * 4;
      areg[i] = *(const float4*)(A + (size_t)(bm + r) * lda + kt * 32 + c4);
    }
  };
  auto writeAf32 = [&](int buf) {
    #pragma unroll
    for (int i = 0; i < 4; ++i) {
      int idx = i * 256 + t, r = idx >> 3, c4 = (idx & 7) * 4;
      int g = (c4 >> 3) ^ ((r >> 1) & 3);
      int off = r * 32 + g * 8 + (c4 & 4);
      bf16x4 h;
      h.x = (__bf16)areg[i].x; h.y = (__bf16)areg[i].y;
      h.z = (__bf16)areg[i].z; h.w = (__bf16)areg[i].w;
      *(u16x4*)&As[buf][off] = *(u16x4*)&h;
    }
  };

  const int nkt = K >> 5;
  if constexpr (A_F32) {
    loadAf32(0); stageB(0, 0);
    VM2;  writeAf32(0);
    VM0; LGKM0; BAR;
  } else {
    stage(0, 0);
    VM0; BAR;
  }

  int cur = 0;
  for (int kt = 0; kt < nkt; ++kt) {
    const bool pf = (kt + 1 < nkt);
    if (pf) {
      if constexpr (A_F32) { loadAf32(kt + 1); stageB(cur ^ 1, kt + 1); }
      else                 { stage(cur ^ 1, kt + 1); }
    }

    bf16x8 a[4], b[4];
    #pragma unroll
    for (int m = 0; m < 4; ++m)
      a[m] = *(const bf16x8*)&As[cur][(wr * 64 + m * 16 + lr) * 32 + rg];
    #pragma unroll
    for (int n = 0; n < 4; ++n)
      b[n] = *(const bf16x8*)&Bs[cur][(wc * 64 + n * 16 + lr) * 32 + rg];
    #pragma unroll
    for (int m = 0; m < 4; ++m)
      #pragma unroll
      for (int n = 0; n < 4; ++n)
        acc[m][n] = __builtin_amdgcn_mfma_f32_16x16x32_bf16(a[m], b[n], acc[m][n], 0, 0, 0);

    if (pf) {
      if constexpr (A_F32) { VM2; writeAf32(cur ^ 1); VM0; LGKM0; }
      else                 { VM0; }
    }
    BAR;
    cur ^= 1;
  }

  const int lq = lane >> 4;
  #pragma unroll
  for (int m = 0; m < 4; ++m) {
    #pragma unroll
    for (int n = 0; n < 4; ++n) {
      int col = bn + wc * 64 + n * 16 + lr;
      float bv = bias[col];
      #pragma unroll
      for (int r = 0; r < 4; ++r) {
        int row = bm + wr * 64 + m * 16 + lq * 4 + r;
        float v = acc[m][n][r] + bv;
        if constexpr (HAS_POS) v += pos[(row % 9) * 512 + col];
        if constexpr (HAS_RES) v += bf2f(res[(size_t)row * res_stride + col]);
        if constexpr (HAS_GELU) v = 0.5f * v * (1.f + erff(v * 0.70710678118f));
        out[(size_t)row * N + col] = f2bf(v);
      }
    }
  }
}

// ---------------------------------------------------------------------------
// LayerNorm over rows of 512 (bf16 in). One wave per row, 4 rows per block.
// ---------------------------------------------------------------------------
__global__ __launch_bounds__(256) void ln_k(
    const u16* in,
    const float* __restrict__ g, const float* __restrict__ be,
    u16* out_bf, float* out_f32, int rows)
{
  int wv = threadIdx.x >> 6, lane = threadIdx.x & 63;
  int row = blockIdx.x * 4 + wv;
  if (row >= rows) return;
  const u16* p = in + (size_t)row * 512;
  u16x8 v = *(const u16x8*)&p[lane * 8];
  float x[8], s = 0.f, sq = 0.f;
  #pragma unroll
  for (int j = 0; j < 8; ++j) { x[j] = bf2f(v[j]); s += x[j]; sq += x[j] * x[j]; }
  #pragma unroll
  for (int o = 32; o > 0; o >>= 1) { s += __shfl_xor(s, o, 64); sq += __shfl_xor(sq, o, 64); }
  float mean = s * (1.f / 512.f);
  float var  = sq * (1.f / 512.f) - mean * mean;
  float rs   = rsqrtf(var + 1e-5f);
  float y[8];
  #pragma unroll
  for (int j = 0; j < 8; ++j) {
    int c = lane * 8 + j;
    y[j] = (x[j] - mean) * rs * g[c] + be[c];
  }
  if (out_bf) {
    u16x8 o8;
    #pragma unroll
    for (int j = 0; j < 8; ++j) o8[j] = f2bf(y[j]);
    *(u16x8*)&out_bf[(size_t)row * 512 + lane * 8] = o8;
  }
  if (out_f32) {
    #pragma unroll
    for (int j = 0; j < 8; ++j) out_f32[(size_t)row * 512 + lane * 8 + j] = y[j];
  }
}

// ---------------------------------------------------------------------------
// Self-attention, one block per sample: qkv[9,1536] (q|k|v), H=8, d=64, L=9.
// ---------------------------------------------------------------------------
__global__ __launch_bounds__(256) void sa_attn_k(const u16* __restrict__ qkv,
                                                 u16* __restrict__ out)
{
  __shared__ u16  s_qkv[9 * 1536];
  __shared__ float s_sc[8][81];
  const int s = blockIdx.x, t = threadIdx.x;
  const u16* src = qkv + (size_t)s * 9 * 1536;
  for (int i = t; i < (9 * 1536) / 8; i += 256)
    *(u16x8*)&s_qkv[i * 8] = *(const u16x8*)&src[i * 8];
  __syncthreads();

  const int h = t >> 5, sl = t & 31;
  for (int p = sl; p < 81; p += 32) {
    int qi = p / 9, ki = p % 9;
    const u16* qp = &s_qkv[qi * 1536 + h * 64];
    const u16* kp = &s_qkv[ki * 1536 + 512 + h * 64];
    float d = 0.f;
    #pragma unroll
    for (int e8 = 0; e8 < 8; ++e8) {
      u16x8 qv = *(const u16x8*)&qp[e8 * 8];
      u16x8 kv = *(const u16x8*)&kp[e8 * 8];
      #pragma unroll
      for (int j = 0; j < 8; ++j) d += bf2f(qv[j]) * bf2f(kv[j]);
    }
    s_sc[h][p] = d * 0.125f;
  }
  __syncthreads();

  if (t < 72) {
    int hh = t / 9, qi = t % 9;
    float* sc = &s_sc[hh][qi * 9];
    float mx = sc[0];
    #pragma unroll
    for (int i = 1; i < 9; ++i) mx = fmaxf(mx, sc[i]);
    float e[9], sum = 0.f;
    #pragma unroll
    for (int i = 0; i < 9; ++i) { e[i] = __expf(sc[i] - mx); sum += e[i]; }
    float inv = 1.f / sum;
    #pragma unroll
    for (int i = 0; i < 9; ++i) sc[i] = e[i] * inv;
  }
  __syncthreads();

  for (int gidx = sl; gidx < 72; gidx += 32) {
    int qi = gidx >> 3, dg = gidx & 7;
    float a[8] = {};
    #pragma unroll
    for (int ki = 0; ki < 9; ++ki) {
      float pr = s_sc[h][qi * 9 + ki];
      u16x8 vv = *(const u16x8*)&s_qkv[ki * 1536 + 1024 + h * 64 + dg * 8];
      #pragma unroll
      for (int j = 0; j < 8; ++j) a[j] += pr * bf2f(vv[j]);
    }
    u16x8 o8;
    #pragma unroll
    for (int j = 0; j < 8; ++j) o8[j] = f2bf(a[j]);
    *(u16x8*)&out[((size_t)s * 9 + qi) * 512 + h * 64 + dg * 8] = o8;
  }
}

// ---------------------------------------------------------------------------
// Cross-attention, one block per sample: q[512], kv[9,1024] (k|v).
// ---------------------------------------------------------------------------
__global__ __launch_bounds__(256) void ca_attn_k(const u16* __restrict__ q,
                                                 const u16* __restrict__ kv,
                                                 u16* __restrict__ out)
{
  __shared__ u16  s_q[512];
  __shared__ u16  s_kv[9 * 1024];
  __shared__ float s_sc[8][9];
  const int s = blockIdx.x, t = threadIdx.x;
  if (t < 64) *(u16x8*)&s_q[t * 8] = *(const u16x8*)&q[(size_t)s * 512 + t * 8];
  for (int i = t; i < (9 * 1024) / 8; i += 256)
    *(u16x8*)&s_kv[i * 8] = *(const u16x8*)&kv[(size_t)s * 9 * 1024 + i * 8];
  __syncthreads();

  if (t < 72) {
    int h = t / 9, ki = t % 9;
    const u16* qp = &s_q[h * 64];
    const u16* kp = &s_kv[ki * 1024 + h * 64];
    float d = 0.f;
    #pragma unroll
    for (int e8 = 0; e8 < 8; ++e8) {
      u16x8 qv = *(const u16x8*)&qp[e8 * 8];
      u16x8 kvv = *(const u16x8*)&kp[e8 * 8];
      #pragma unroll
      for (int j = 0; j < 8; ++j) d += bf2f(qv[j]) * bf2f(kvv[j]);
    }
    s_sc[h][ki] = d * 0.125f;
  }
  __syncthreads();

  if (t < 8) {
    float* sc = s_sc[t];
    float mx = sc[0];
    #pragma unroll
    for (int i = 1; i < 9; ++i) mx = fmaxf(mx, sc[i]);
    float e[9], sum = 0.f;
    #pragma unroll
    for (int i = 0; i < 9; ++i) { e[i] = __expf(sc[i] - mx); sum += e[i]; }
    float inv = 1.f / sum;
    #pragma unroll
    for (int i = 0; i < 9; ++i) sc[i] = e[i] * inv;
  }
  __syncthreads();

  if (t < 64) {
    int h = t >> 3, dg = t & 7;
    float a[8] = {};
    #pragma unroll
    for (int ki = 0; ki < 9; ++ki) {
      float pr = s_sc[h][ki];
      u16x8 vv = *(const u16x8*)&s_kv[ki * 1024 + 512 + h * 64 + dg * 8];
      #pragma unroll
      for (int j = 0; j < 8; ++j) a[j] += pr * bf2f(vv[j]);
    }
    u16x8 o8;
    #pragma unroll
    for (int j = 0; j < 8; ++j) o8[j] = f2bf(a[j]);
    *(u16x8*)&out[(size_t)s * 512 + h * 64 + dg * 8] = o8;
  }
}

// ---------------------------------------------------------------------------
// Fused weight conversion: all 7 f32 weight tensors -> contiguous bf16 region.
// ---------------------------------------------------------------------------
__global__ __launch_bounds__(256) void wcvt_k(
    const float* s0, const float* s1, const float* s2, const float* s3,
    const float* s4, const float* s5, const float* s6, u16* dst)
{
  int b = blockIdx.x;
  const float* sp; long base, segStart;
  if      (b < 384)  { sp = s0; base = 0;       segStart = 0;    }
  else if (b < 1152) { sp = s1; base = 393216;  segStart = 384;  }
  else if (b < 1408) { sp = s2; base = 1179648; segStart = 1152; }
  else if (b < 2176) { sp = s3; base = 1441792; segStart = 1408; }
  else if (b < 2432) { sp = s4; base = 2228224; segStart = 2176; }
  else if (b < 3456) { sp = s5; base = 2490368; segStart = 2432; }
  else               { sp = s6; base = 3538944; segStart = 3456; }
  long loc = ((long)b - segStart) * 1024 + (long)threadIdx.x * 4;
  float4 f = *(const float4*)(sp + loc);
  u16x4 o; o.x = f2bf(f.x); o.y = f2bf(f.y); o.z = f2bf(f.z); o.w = f2bf(f.w);
  *(u16x4*)&dst[base + loc] = o;
}

// ---------------------------------------------------------------------------
// Host launcher
// ---------------------------------------------------------------------------
extern "C" void kernel_launch(void* const* d_in, const int* in_sizes, int n_in,
                              void* d_out, int out_size, void* d_ws, size_t ws_size,
                              hipStream_t stream)
{
  const float* patches  = (const float*)d_in[0];
  const float* w_pe     = (const float*)d_in[1];
  const float* b_pe     = (const float*)d_in[2];
  const float* pos      = (const float*)d_in[3];
  const float* sa_in_w  = (const float*)d_in[4];
  const float* sa_in_b  = (const float*)d_in[5];
  const float* sa_out_w = (const float*)d_in[6];
  const float* sa_out_b = (const float*)d_in[7];
  const float* g1       = (const float*)d_in[8];
  const float* beta1    = (const float*)d_in[9];
  const float* ca_in_w  = (const float*)d_in[10];
  const float* ca_in_b  = (const float*)d_in[11];
  const float* ca_out_w = (const float*)d_in[12];
  const float* ca_out_b = (const float*)d_in[13];
  const float* g2       = (const float*)d_in[14];
  const float* beta2    = (const float*)d_in[15];
  const float* w1       = (const float*)d_in[16];
  const float* b1       = (const float*)d_in[17];
  const float* w2       = (const float*)d_in[18];
  const float* b2       = (const float*)d_in[19];
  const float* g3       = (const float*)d_in[20];
  const float* beta3    = (const float*)d_in[21];
  float* out = (float*)d_out;

  // workspace layout (bytes)
  char* base = (char*)d_ws;
  u16* wbf        = (u16*)base;
  u16* w_pe_bf    = wbf;
  u16* sa_in_bf   = wbf + 393216;
  u16* sa_out_bf  = wbf + 1179648;
  u16* ca_in_bf   = wbf + 1441792;
  u16* ca_out_bf  = wbf + 2228224;
  u16* w1_bf      = wbf + 2490368;
  u16* w2_bf      = wbf + 3538944;
  u16* x_bf  = (u16*)(base + 9175040ull);     // [73728,512]
  u16* qkv   = (u16*)(base + 84672512ull);    // [73728,1536]; also CA kv
  u16* sattn = (u16*)(base + 311164928ull);   // [73728,512]
  u16* q_bf  = (u16*)(base + 386662400ull);   // [8192,512]
  u16* cattn = (u16*)(base + 395051008ull);   // [8192,512]
  u16* csum  = (u16*)(base + 403439616ull);   // [8192,512]
  u16* h_bf  = (u16*)(base + 411828224ull);   // [8192,2048]
  u16* osum  = (u16*)(base + 445382656ull);   // [8192,512]

  // all weights -> bf16 in one kernel
  wcvt_k<<<4480, 256, 0, stream>>>(w_pe, sa_in_w, sa_out_w, ca_in_w,
                                   ca_out_w, w1, w2, wbf);

  // 1. patch embed + bias + pos_embed -> x_bf  (f32 A fused in staging)
  gemm_k2<true, true, false, false><<<2304, 256, 0, stream>>>(
      patches, 768, w_pe_bf, b_pe, pos, nullptr, 0, x_bf, 73728, 512, 768, 4);
  // 2. SA qkv (256-tall tile: 288 x 12 blocks)
  gemm_t<false, false><<<3456, 512, 0, stream>>>(
      x_bf, 512, sa_in_bf, sa_in_b, nullptr, 0, qkv, 73728, 1536, 512, 12);
  // 3. SA attention
  sa_attn_k<<<8192, 256, 0, stream>>>(qkv, sattn);
  // 4. SA out proj + residual(x) -> x_bf (elementwise in-place)
  gemm_t<true, false><<<1152, 512, 0, stream>>>(
      sattn, 512, sa_out_bf, sa_out_b, x_bf, 512, x_bf, 73728, 512, 512, 4);
  // 5. LN1 (in place)
  ln_k<<<73728 / 4, 256, 0, stream>>>(x_bf, g1, beta1, x_bf, nullptr, 73728);
  // 6. CA q from center token (row stride 9*512, offset 4*512)
  gemm_k2<false, false, false, false><<<256, 256, 0, stream>>>(
      x_bf + 2048, 4608, ca_in_bf, ca_in_b, nullptr, nullptr, 0, q_bf, 8192, 512, 512, 4);
  // 7. CA kv (wk|wv = ca_in_w rows 512..1535)
  gemm_t<false, false><<<2304, 512, 0, stream>>>(
      x_bf, 512, ca_in_bf + 262144, ca_in_b + 512, nullptr, 0, qkv, 73728, 1024, 512, 8);
  // 8. CA attention
  ca_attn_k<<<8192, 256, 0, stream>>>(q_bf, qkv, cattn);
  // 9. CA out proj + residual(cq) -> csum
  gemm_k2<false, false, true, false><<<256, 256, 0, stream>>>(
      cattn, 512, ca_out_bf, ca_out_b, nullptr, x_bf + 2048, 4608, csum, 8192, 512, 512, 4);
  // 10. LN2 (in place) -> c
  ln_k<<<8192 / 4, 256, 0, stream>>>(csum, g2, beta2, csum, nullptr, 8192);
  // 11. FFN1 + exact GELU -> h_bf (32 x 16 blocks)
  gemm_t<false, true><<<512, 512, 0, stream>>>(
      csum, 512, w1_bf, b1, nullptr, 0, h_bf, 8192, 2048, 512, 16);
  // 12. FFN2 + residual(c) -> osum
  gemm_k2<false, false, true, false><<<256, 256, 0, stream>>>(
      h_bf, 2048, w2_bf, b2, nullptr, csum, 512, osum, 8192, 512, 2048, 4);
  // 13. LN3 -> d_out (f32)
  ln_k<<<8192 / 4, 256, 0, stream>>>(osum, g3, beta3, nullptr, out, 8192);
}

// Round 11
// 752.943 us; speedup vs baseline: 1.0395x; 1.0205x over previous
//
#include <hip/hip_runtime.h>

// ---------------------------------------------------------------------------
// NeighborEmbedder on MI355X (gfx950). Round 11:
//  - gemm_pe: PE kernel with TRUE reg-depth-2 for the f32 A stream (2 areg
//    sets, parity-unrolled loop): A loads get a full iteration of flight
//    instead of one MFMA phase -> kills the per-kt VM stall (was MfmaUtil 15%).
//  - gemm_s: 64x128 tile for the M=8192/N=512 GEMMs (CAq/CAproj/FFN2):
//    grid 256->512 blocks, 2+ blocks/CU instead of 1.
//  - gemm_t (qkv/SAproj/CAkv/FFN1), attention, LN, wcvt unchanged from R10.
// ---------------------------------------------------------------------------

typedef unsigned short u16;
typedef u16   u16x8 __attribute__((ext_vector_type(8)));
typedef u16   u16x4 __attribute__((ext_vector_type(4)));
typedef __bf16 bf16x8 __attribute__((ext_vector_type(8)));
typedef __bf16 bf16x4 __attribute__((ext_vector_type(4)));
typedef float f32x4 __attribute__((ext_vector_type(4)));

static __device__ __forceinline__ u16 f2bf(float f) {
  union { float f; unsigned u; } v; v.f = f;
  unsigned r = v.u + 0x7FFFu + ((v.u >> 16) & 1u);   // RNE
  return (u16)(r >> 16);
}
static __device__ __forceinline__ float bf2f(u16 u) {
  union { unsigned u; float f; } v; v.u = ((unsigned)u) << 16;
  return v.f;
}

// async global->LDS, 16B per lane. LDS dest wave-uniform base + lane*16.
static __device__ __forceinline__ void gld16(const void* g, void* l) {
  __builtin_amdgcn_global_load_lds(
      (__attribute__((address_space(1))) unsigned int*)(size_t)g,
      (__attribute__((address_space(3))) unsigned int*)(unsigned)(size_t)l,
      16, 0, 0);
}

// bijective XCD-chunked swizzle (m204)
static __device__ __forceinline__ int xcd_swz(int bid, int nwg) {
  int q = nwg >> 3, r = nwg & 7;
  int xcd = bid & 7, sub = bid >> 3;
  return (xcd < r ? xcd * (q + 1) : r * (q + 1) + (xcd - r) * q) + sub;
}

#define BAR   __builtin_amdgcn_s_barrier()
#define VM0   asm volatile("s_waitcnt vmcnt(0)" ::: "memory")
#define VM4   asm volatile("s_waitcnt vmcnt(4)" ::: "memory")
#define VM6   asm volatile("s_waitcnt vmcnt(6)" ::: "memory")
#define LGKM0 asm volatile("s_waitcnt lgkmcnt(0)" ::: "memory")

// ---------------------------------------------------------------------------
// gemm_pe: x[M,512] = patches_f32[M,768] @ Wpe^T + bias + pos  (PE only)
// 128x128 tile, BK=32, 256 thr = 4 waves. Reg-depth-2 on the f32 A stream:
//   iter kt: VM0 -> writeA(kt+1 regs, loaded LAST iter) -> stageB(kt+1)
//            -> loadA(kt+2) -> MFMA(kt) -> VM4 (drain B only) -> BAR
// Queue discipline: [B(kt+1) x2, A(kt+2) x4]; VM4 leaves A flying a full iter.
// Parity-unrolled kt loop so areg set index is compile-time (rule #20).
// Requires K%64==0.
// ---------------------------------------------------------------------------
__global__ __launch_bounds__(256, 3) void gemm_pe(
    const float* __restrict__ A, int lda,
    const u16* __restrict__ W,
    const float* __restrict__ bias,
    const float* __restrict__ pos,
    u16* out, int M, int N, int K, int nbx)
{
  __shared__ u16 As[2][4096];
  __shared__ u16 Bs[2][4096];

  const int t    = threadIdx.x;
  const int lane = t & 63, wv = t >> 6;
  const int swz  = xcd_swz(blockIdx.x, gridDim.x);
  const int bm   = (swz / nbx) * 128, bn = (swz % nbx) * 128;
  const int wr   = wv >> 1, wc = wv & 1;

  const int srow = lane >> 2;
  const int skk  = (((lane & 3) ^ ((lane >> 3) & 3)) << 3);
  const int lr = lane & 15;
  const int rg = (((lane >> 4) ^ ((lr >> 1) & 3)) << 3);

  f32x4 acc[4][4] = {};
  float4 areg0[4], areg1[4];

  auto stageB = [&](int buf, int kt) {         // 2 gld16 per wave
    #pragma unroll
    for (int c = 0; c < 2; ++c) {
      int rr = (wv + 4 * c) * 16 + srow;
      gld16(W + (size_t)(bn + rr) * K + kt * 32 + skk, &Bs[buf][(wv + 4 * c) * 512]);
    }
  };
  auto loadA = [&](float4 (&dst)[4], int kt) { // 4 float4 per thread
    #pragma unroll
    for (int i = 0; i < 4; ++i) {
      int idx = i * 256 + t, r = idx >> 3, c4 = (idx & 7) * 4;
      dst[i] = *(const float4*)(A + (size_t)(bm + r) * lda + kt * 32 + c4);
    }
  };
  auto writeA = [&](int buf, float4 (&src)[4]) {  // cvt + swizzled ds_write
    #pragma unroll
    for (int i = 0; i < 4; ++i) {
      int idx = i * 256 + t, r = idx >> 3, c4 = (idx & 7) * 4;
      int g = (c4 >> 3) ^ ((r >> 1) & 3);
      int off = r * 32 + g * 8 + (c4 & 4);
      bf16x4 h;
      h.x = (__bf16)src[i].x; h.y = (__bf16)src[i].y;
      h.z = (__bf16)src[i].z; h.w = (__bf16)src[i].w;
      *(u16x4*)&As[buf][off] = *(u16x4*)&h;
    }
  };
  auto mfma_on = [&](int cur) {
    bf16x8 a[4], b[4];
    #pragma unroll
    for (int m = 0; m < 4; ++m)
      a[m] = *(const bf16x8*)&As[cur][(wr * 64 + m * 16 + lr) * 32 + rg];
    #pragma unroll
    for (int n = 0; n < 4; ++n)
      b[n] = *(const bf16x8*)&Bs[cur][(wc * 64 + n * 16 + lr) * 32 + rg];
    #pragma unroll
    for (int m = 0; m < 4; ++m)
      #pragma unroll
      for (int n = 0; n < 4; ++n)
        acc[m][n] = __builtin_amdgcn_mfma_f32_16x16x32_bf16(a[m], b[n], acc[m][n], 0, 0, 0);
  };

  const int nkt = K >> 5;                 // even (K%64==0)
  // ---- prologue: A0->set0, B0->buf0, A1->set1; complete buf0; A1 flying
  loadA(areg0, 0);                        // queue: A0(4)
  stageB(0, 0);                           // queue: A0(4) B0(2)
  loadA(areg1, 1);                        // queue: A0(4) B0(2) A1(4)
  VM6;                                    // drain A0
  writeA(0, areg0);
  VM4;                                    // drain B0 (A1 keeps flying)
  LGKM0; BAR;

  auto iter = [&](int kt, float4 (&wset)[4], float4 (&lset)[4]) {
    const bool pf1 = kt + 1 < nkt, pf2 = kt + 2 < nkt;
    const int cur = kt & 1;
    if (pf1) {
      VM0;                                // A(kt+1) regs arrived (1 iter old)
      writeA(cur ^ 1, wset);
      stageB(cur ^ 1, kt + 1);            // B first in queue
    }
    if (pf2) loadA(lset, kt + 2);         // A(kt+2) after B in queue
    mfma_on(cur);
    if (pf1) { if (pf2) { VM4; } else { VM0; } }
    LGKM0; BAR;
  };
  for (int kt = 0; kt < nkt; kt += 2) {
    iter(kt,     areg1, areg0);           // writes A(kt+1)=set1, loads into set0
    iter(kt + 1, areg0, areg1);           // writes A(kt+2)=set0, loads into set1
  }

  // epilogue: row=(lane>>4)*4+r (+m*16), col=lane&15 (+n*16)  [m89 layout]
  const int lq = lane >> 4;
  #pragma unroll
  for (int m = 0; m < 4; ++m) {
    #pragma unroll
    for (int n = 0; n < 4; ++n) {
      int col = bn + wc * 64 + n * 16 + lr;
      float bv = bias[col];
      #pragma unroll
      for (int r = 0; r < 4; ++r) {
        int row = bm + wr * 64 + m * 16 + lq * 4 + r;
        float v = acc[m][n][r] + bv + pos[(row % 9) * 512 + col];
        out[(size_t)row * N + col] = f2bf(v);
      }
    }
  }
}

// ---------------------------------------------------------------------------
// gemm_t: 256x128 tile, 8 waves (R10, unchanged) for qkv/SAproj/CAkv/FFN1.
// ---------------------------------------------------------------------------
template<bool HAS_RES, bool HAS_GELU>
__global__ __launch_bounds__(512, 4) void gemm_t(
    const u16* __restrict__ A, int lda,
    const u16* __restrict__ W,
    const float* __restrict__ bias,
    const u16* res, int res_stride,
    u16* out,
    int M, int N, int K, int nbx)
{
  __shared__ u16 As[2][8192];
  __shared__ u16 Bs[2][4096];

  const int t    = threadIdx.x;
  const int lane = t & 63, wv = t >> 6;
  const int swz  = xcd_swz(blockIdx.x, gridDim.x);
  const int bm   = (swz / nbx) * 256, bn = (swz % nbx) * 128;
  const int wr   = wv >> 1, wc = wv & 1;

  const int srow = lane >> 2;
  const int skk  = (((lane & 3) ^ ((lane >> 3) & 3)) << 3);
  const int lr = lane & 15;
  const int rg = (((lane >> 4) ^ ((lr >> 1) & 3)) << 3);

  f32x4 acc[4][4] = {};

  auto stage = [&](int buf, int kt) {
    #pragma unroll
    for (int c = 0; c < 2; ++c) {
      int rr = wv * 32 + c * 16 + srow;
      gld16(A + (size_t)(bm + rr) * lda + kt * 32 + skk,
            &As[buf][(wv * 2 + c) * 512]);
    }
    int rb = wv * 16 + srow;
    gld16(W + (size_t)(bn + rb) * K + kt * 32 + skk, &Bs[buf][wv * 512]);
  };

  const int nkt = K >> 5;
  stage(0, 0);
  VM0; BAR;

  int cur = 0;
  for (int kt = 0; kt < nkt; ++kt) {
    const bool pf = (kt + 1 < nkt);
    if (pf) stage(cur ^ 1, kt + 1);

    bf16x8 a[4], b[4];
    #pragma unroll
    for (int m = 0; m < 4; ++m)
      a[m] = *(const bf16x8*)&As[cur][(wr * 64 + m * 16 + lr) * 32 + rg];
    #pragma unroll
    for (int n = 0; n < 4; ++n)
      b[n] = *(const bf16x8*)&Bs[cur][(wc * 64 + n * 16 + lr) * 32 + rg];
    #pragma unroll
    for (int m = 0; m < 4; ++m)
      #pragma unroll
      for (int n = 0; n < 4; ++n)
        acc[m][n] = __builtin_amdgcn_mfma_f32_16x16x32_bf16(a[m], b[n], acc[m][n], 0, 0, 0);

    if (pf) VM0;
    BAR;
    cur ^= 1;
  }

  const int lq = lane >> 4;
  #pragma unroll
  for (int m = 0; m < 4; ++m) {
    #pragma unroll
    for (int n = 0; n < 4; ++n) {
      int col = bn + wc * 64 + n * 16 + lr;
      float bv = bias[col];
      #pragma unroll
      for (int r = 0; r < 4; ++r) {
        int row = bm + wr * 64 + m * 16 + lq * 4 + r;
        float v = acc[m][n][r] + bv;
        if constexpr (HAS_RES) v += bf2f(res[(size_t)row * res_stride + col]);
        if constexpr (HAS_GELU) v = 0.5f * v * (1.f + erff(v * 0.70710678118f));
        out[(size_t)row * N + col] = f2bf(v);
      }
    }
  }
}

// ---------------------------------------------------------------------------
// gemm_s: 64x128 tile, 256 thr = 4 waves (1M x 4N), per-wave 64x32
// (acc[4][2] = 32 AGPR). 24 KB LDS, depth-1 prefetch. For the small
// M=8192/N=512 GEMMs: doubles the grid to 512 blocks (2+ blocks/CU).
// Requires M%64==0, N%128==0, K%32==0.
// ---------------------------------------------------------------------------
template<bool HAS_RES, bool HAS_GELU>
__global__ __launch_bounds__(256, 6) void gemm_s(
    const u16* __restrict__ A, int lda,
    const u16* __restrict__ W,
    const float* __restrict__ bias,
    const u16* res, int res_stride,
    u16* out,
    int M, int N, int K, int nbx)
{
  __shared__ u16 As[2][2048];   // 64x32 bf16 = 4 KB
  __shared__ u16 Bs[2][4096];   // 128x32 bf16 = 8 KB

  const int t    = threadIdx.x;
  const int lane = t & 63, wv = t >> 6;
  const int swz  = xcd_swz(blockIdx.x, gridDim.x);
  const int bm   = (swz / nbx) * 64, bn = (swz % nbx) * 128;
  const int wc   = wv;                        // wave -> 32-col slice

  const int srow = lane >> 2;
  const int skk  = (((lane & 3) ^ ((lane >> 3) & 3)) << 3);
  const int lr = lane & 15;
  const int rg = (((lane >> 4) ^ ((lr >> 1) & 3)) << 3);

  f32x4 acc[4][2] = {};

  auto stage = [&](int buf, int kt) {          // 3 gld16 per wave
    gld16(A + (size_t)(bm + wv * 16 + srow) * lda + kt * 32 + skk,
          &As[buf][wv * 512]);
    #pragma unroll
    for (int c = 0; c < 2; ++c) {
      int rr = (wv + 4 * c) * 16 + srow;
      gld16(W + (size_t)(bn + rr) * K + kt * 32 + skk, &Bs[buf][(wv + 4 * c) * 512]);
    }
  };

  const int nkt = K >> 5;
  stage(0, 0);
  VM0; BAR;

  int cur = 0;
  for (int kt = 0; kt < nkt; ++kt) {
    const bool pf = (kt + 1 < nkt);
    if (pf) stage(cur ^ 1, kt + 1);

    bf16x8 a[4], b[2];
    #pragma unroll
    for (int m = 0; m < 4; ++m)
      a[m] = *(const bf16x8*)&As[cur][(m * 16 + lr) * 32 + rg];
    #pragma unroll
    for (int n = 0; n < 2; ++n)
      b[n] = *(const bf16x8*)&Bs[cur][(wc * 32 + n * 16 + lr) * 32 + rg];
    #pragma unroll
    for (int m = 0; m < 4; ++m)
      #pragma unroll
      for (int n = 0; n < 2; ++n)
        acc[m][n] = __builtin_amdgcn_mfma_f32_16x16x32_bf16(a[m], b[n], acc[m][n], 0, 0, 0);

    if (pf) VM0;
    BAR;
    cur ^= 1;
  }

  const int lq = lane >> 4;
  #pragma unroll
  for (int m = 0; m < 4; ++m) {
    #pragma unroll
    for (int n = 0; n < 2; ++n) {
      int col = bn + wc * 32 + n * 16 + lr;
      float bv = bias[col];
      #pragma unroll
      for (int r = 0; r < 4; ++r) {
        int row = bm + m * 16 + lq * 4 + r;
        float v = acc[m][n][r] + bv;
        if constexpr (HAS_RES) v += bf2f(res[(size_t)row * res_stride + col]);
        if constexpr (HAS_GELU) v = 0.5f * v * (1.f + erff(v * 0.70710678118f));
        out[(size_t)row * N + col] = f2bf(v);
      }
    }
  }
}

// ---------------------------------------------------------------------------
// LayerNorm over rows of 512 (bf16 in). One wave per row, 4 rows per block.
// ---------------------------------------------------------------------------
__global__ __launch_bounds__(256) void ln_k(
    const u16* in,
    const float* __restrict__ g, const float* __restrict__ be,
    u16* out_bf, float* out_f32, int rows)
{
  int wv = threadIdx.x >> 6, lane = threadIdx.x & 63;
  int row = blockIdx.x * 4 + wv;
  if (row >= rows) return;
  const u16* p = in + (size_t)row * 512;
  u16x8 v = *(const u16x8*)&p[lane * 8];
  float x[8], s = 0.f, sq = 0.f;
  #pragma unroll
  for (int j = 0; j < 8; ++j) { x[j] = bf2f(v[j]); s += x[j]; sq += x[j] * x[j]; }
  #pragma unroll
  for (int o = 32; o > 0; o >>= 1) { s += __shfl_xor(s, o, 64); sq += __shfl_xor(sq, o, 64); }
  float mean = s * (1.f / 512.f);
  float var  = sq * (1.f / 512.f) - mean * mean;
  float rs   = rsqrtf(var + 1e-5f);
  float y[8];
  #pragma unroll
  for (int j = 0; j < 8; ++j) {
    int c = lane * 8 + j;
    y[j] = (x[j] - mean) * rs * g[c] + be[c];
  }
  if (out_bf) {
    u16x8 o8;
    #pragma unroll
    for (int j = 0; j < 8; ++j) o8[j] = f2bf(y[j]);
    *(u16x8*)&out_bf[(size_t)row * 512 + lane * 8] = o8;
  }
  if (out_f32) {
    #pragma unroll
    for (int j = 0; j < 8; ++j) out_f32[(size_t)row * 512 + lane * 8 + j] = y[j];
  }
}

// ---------------------------------------------------------------------------
// Self-attention, one block per sample: qkv[9,1536] (q|k|v), H=8, d=64, L=9.
// ---------------------------------------------------------------------------
__global__ __launch_bounds__(256) void sa_attn_k(const u16* __restrict__ qkv,
                                                 u16* __restrict__ out)
{
  __shared__ u16  s_qkv[9 * 1536];
  __shared__ float s_sc[8][81];
  const int s = blockIdx.x, t = threadIdx.x;
  const u16* src = qkv + (size_t)s * 9 * 1536;
  for (int i = t; i < (9 * 1536) / 8; i += 256)
    *(u16x8*)&s_qkv[i * 8] = *(const u16x8*)&src[i * 8];
  __syncthreads();

  const int h = t >> 5, sl = t & 31;
  for (int p = sl; p < 81; p += 32) {
    int qi = p / 9, ki = p % 9;
    const u16* qp = &s_qkv[qi * 1536 + h * 64];
    const u16* kp = &s_qkv[ki * 1536 + 512 + h * 64];
    float d = 0.f;
    #pragma unroll
    for (int e8 = 0; e8 < 8; ++e8) {
      u16x8 qv = *(const u16x8*)&qp[e8 * 8];
      u16x8 kv = *(const u16x8*)&kp[e8 * 8];
      #pragma unroll
      for (int j = 0; j < 8; ++j) d += bf2f(qv[j]) * bf2f(kv[j]);
    }
    s_sc[h][p] = d * 0.125f;
  }
  __syncthreads();

  if (t < 72) {
    int hh = t / 9, qi = t % 9;
    float* sc = &s_sc[hh][qi * 9];
    float mx = sc[0];
    #pragma unroll
    for (int i = 1; i < 9; ++i) mx = fmaxf(mx, sc[i]);
    float e[9], sum = 0.f;
    #pragma unroll
    for (int i = 0; i < 9; ++i) { e[i] = __expf(sc[i] - mx); sum += e[i]; }
    float inv = 1.f / sum;
    #pragma unroll
    for (int i = 0; i < 9; ++i) sc[i] = e[i] * inv;
  }
  __syncthreads();

  for (int gidx = sl; gidx < 72; gidx += 32) {
    int qi = gidx >> 3, dg = gidx & 7;
    float a[8] = {};
    #pragma unroll
    for (int ki = 0; ki < 9; ++ki) {
      float pr = s_sc[h][qi * 9 + ki];
      u16x8 vv = *(const u16x8*)&s_qkv[ki * 1536 + 1024 + h * 64 + dg * 8];
      #pragma unroll
      for (int j = 0; j < 8; ++j) a[j] += pr * bf2f(vv[j]);
    }
    u16x8 o8;
    #pragma unroll
    for (int j = 0; j < 8; ++j) o8[j] = f2bf(a[j]);
    *(u16x8*)&out[((size_t)s * 9 + qi) * 512 + h * 64 + dg * 8] = o8;
  }
}

// ---------------------------------------------------------------------------
// Cross-attention, one block per sample: q[512], kv[9,1024] (k|v).
// ---------------------------------------------------------------------------
__global__ __launch_bounds__(256) void ca_attn_k(const u16* __restrict__ q,
                                                 const u16* __restrict__ kv,
                                                 u16* __restrict__ out)
{
  __shared__ u16  s_q[512];
  __shared__ u16  s_kv[9 * 1024];
  __shared__ float s_sc[8][9];
  const int s = blockIdx.x, t = threadIdx.x;
  if (t < 64) *(u16x8*)&s_q[t * 8] = *(const u16x8*)&q[(size_t)s * 512 + t * 8];
  for (int i = t; i < (9 * 1024) / 8; i += 256)
    *(u16x8*)&s_kv[i * 8] = *(const u16x8*)&kv[(size_t)s * 9 * 1024 + i * 8];
  __syncthreads();

  if (t < 72) {
    int h = t / 9, ki = t % 9;
    const u16* qp = &s_q[h * 64];
    const u16* kp = &s_kv[ki * 1024 + h * 64];
    float d = 0.f;
    #pragma unroll
    for (int e8 = 0; e8 < 8; ++e8) {
      u16x8 qv = *(const u16x8*)&qp[e8 * 8];
      u16x8 kvv = *(const u16x8*)&kp[e8 * 8];
      #pragma unroll
      for (int j = 0; j < 8; ++j) d += bf2f(qv[j]) * bf2f(kvv[j]);
    }
    s_sc[h][ki] = d * 0.125f;
  }
  __syncthreads();

  if (t < 8) {
    float* sc = s_sc[t];
    float mx = sc[0];
    #pragma unroll
    for (int i = 1; i < 9; ++i) mx = fmaxf(mx, sc[i]);
    float e[9], sum = 0.f;
    #pragma unroll
    for (int i = 0; i < 9; ++i) { e[i] = __expf(sc[i] - mx); sum += e[i]; }
    float inv = 1.f / sum;
    #pragma unroll
    for (int i = 0; i < 9; ++i) sc[i] = e[i] * inv;
  }
  __syncthreads();

  if (t < 64) {
    int h = t >> 3, dg = t & 7;
    float a[8] = {};
    #pragma unroll
    for (int ki = 0; ki < 9; ++ki) {
      float pr = s_sc[h][ki];
      u16x8 vv = *(const u16x8*)&s_kv[ki * 1024 + 512 + h * 64 + dg * 8];
      #pragma unroll
      for (int j = 0; j < 8; ++j) a[j] += pr * bf2f(vv[j]);
    }
    u16x8 o8;
    #pragma unroll
    for (int j = 0; j < 8; ++j) o8[j] = f2bf(a[j]);
    *(u16x8*)&out[(size_t)s * 512 + h * 64 + dg * 8] = o8;
  }
}

// ---------------------------------------------------------------------------
// Fused weight conversion: all 7 f32 weight tensors -> contiguous bf16 region.
// ---------------------------------------------------------------------------
__global__ __launch_bounds__(256) void wcvt_k(
    const float* s0, const float* s1, const float* s2, const float* s3,
    const float* s4, const float* s5, const float* s6, u16* dst)
{
  int b = blockIdx.x;
  const float* sp; long base, segStart;
  if      (b < 384)  { sp = s0; base = 0;       segStart = 0;    }
  else if (b < 1152) { sp = s1; base = 393216;  segStart = 384;  }
  else if (b < 1408) { sp = s2; base = 1179648; segStart = 1152; }
  else if (b < 2176) { sp = s3; base = 1441792; segStart = 1408; }
  else if (b < 2432) { sp = s4; base = 2228224; segStart = 2176; }
  else if (b < 3456) { sp = s5; base = 2490368; segStart = 2432; }
  else               { sp = s6; base = 3538944; segStart = 3456; }
  long loc = ((long)b - segStart) * 1024 + (long)threadIdx.x * 4;
  float4 f = *(const float4*)(sp + loc);
  u16x4 o; o.x = f2bf(f.x); o.y = f2bf(f.y); o.z = f2bf(f.z); o.w = f2bf(f.w);
  *(u16x4*)&dst[base + loc] = o;
}

// ---------------------------------------------------------------------------
// Host launcher
// ---------------------------------------------------------------------------
extern "C" void kernel_launch(void* const* d_in, const int* in_sizes, int n_in,
                              void* d_out, int out_size, void* d_ws, size_t ws_size,
                              hipStream_t stream)
{
  const float* patches  = (const float*)d_in[0];
  const float* w_pe     = (const float*)d_in[1];
  const float* b_pe     = (const float*)d_in[2];
  const float* pos      = (const float*)d_in[3];
  const float* sa_in_w  = (const float*)d_in[4];
  const float* sa_in_b  = (const float*)d_in[5];
  const float* sa_out_w = (const float*)d_in[6];
  const float* sa_out_b = (const float*)d_in[7];
  const float* g1       = (const float*)d_in[8];
  const float* beta1    = (const float*)d_in[9];
  const float* ca_in_w  = (const float*)d_in[10];
  const float* ca_in_b  = (const float*)d_in[11];
  const float* ca_out_w = (const float*)d_in[12];
  const float* ca_out_b = (const float*)d_in[13];
  const float* g2       = (const float*)d_in[14];
  const float* beta2    = (const float*)d_in[15];
  const float* w1       = (const float*)d_in[16];
  const float* b1       = (const float*)d_in[17];
  const float* w2       = (const float*)d_in[18];
  const float* b2       = (const float*)d_in[19];
  const float* g3       = (const float*)d_in[20];
  const float* beta3    = (const float*)d_in[21];
  float* out = (float*)d_out;

  // workspace layout (bytes)
  char* base = (char*)d_ws;
  u16* wbf        = (u16*)base;
  u16* w_pe_bf    = wbf;
  u16* sa_in_bf   = wbf + 393216;
  u16* sa_out_bf  = wbf + 1179648;
  u16* ca_in_bf   = wbf + 1441792;
  u16* ca_out_bf  = wbf + 2228224;
  u16* w1_bf      = wbf + 2490368;
  u16* w2_bf      = wbf + 3538944;
  u16* x_bf  = (u16*)(base + 9175040ull);     // [73728,512]
  u16* qkv   = (u16*)(base + 84672512ull);    // [73728,1536]; also CA kv
  u16* sattn = (u16*)(base + 311164928ull);   // [73728,512]
  u16* q_bf  = (u16*)(base + 386662400ull);   // [8192,512]
  u16* cattn = (u16*)(base + 395051008ull);   // [8192,512]
  u16* csum  = (u16*)(base + 403439616ull);   // [8192,512]
  u16* h_bf  = (u16*)(base + 411828224ull);   // [8192,2048]
  u16* osum  = (u16*)(base + 445382656ull);   // [8192,512]

  // all weights -> bf16 in one kernel
  wcvt_k<<<4480, 256, 0, stream>>>(w_pe, sa_in_w, sa_out_w, ca_in_w,
                                   ca_out_w, w1, w2, wbf);

  // 1. patch embed + bias + pos_embed -> x_bf  (reg-depth-2 f32 pipeline)
  gemm_pe<<<2304, 256, 0, stream>>>(
      patches, 768, w_pe_bf, b_pe, pos, x_bf, 73728, 512, 768, 4);
  // 2. SA qkv
  gemm_t<false, false><<<3456, 512, 0, stream>>>(
      x_bf, 512, sa_in_bf, sa_in_b, nullptr, 0, qkv, 73728, 1536, 512, 12);
  // 3. SA attention
  sa_attn_k<<<8192, 256, 0, stream>>>(qkv, sattn);
  // 4. SA out proj + residual(x) -> x_bf (elementwise in-place)
  gemm_t<true, false><<<1152, 512, 0, stream>>>(
      sattn, 512, sa_out_bf, sa_out_b, x_bf, 512, x_bf, 73728, 512, 512, 4);
  // 5. LN1 (in place)
  ln_k<<<73728 / 4, 256, 0, stream>>>(x_bf, g1, beta1, x_bf, nullptr, 73728);
  // 6. CA q from center token (row stride 9*512, offset 4*512)
  gemm_s<false, false><<<512, 256, 0, stream>>>(
      x_bf + 2048, 4608, ca_in_bf, ca_in_b, nullptr, 0, q_bf, 8192, 512, 512, 4);
  // 7. CA kv (wk|wv = ca_in_w rows 512..1535)
  gemm_t<false, false><<<2304, 512, 0, stream>>>(
      x_bf, 512, ca_in_bf + 262144, ca_in_b + 512, nullptr, 0, qkv, 73728, 1024, 512, 8);
  // 8. CA attention
  ca_attn_k<<<8192, 256, 0, stream>>>(q_bf, qkv, cattn);
  // 9. CA out proj + residual(cq) -> csum
  gemm_s<true, false><<<512, 256, 0, stream>>>(
      cattn, 512, ca_out_bf, ca_out_b, x_bf + 2048, 4608, csum, 8192, 512, 512, 4);
  // 10. LN2 (in place) -> c
  ln_k<<<8192 / 4, 256, 0, stream>>>(csum, g2, beta2, csum, nullptr, 8192);
  // 11. FFN1 + exact GELU -> h_bf
  gemm_t<false, true><<<512, 512, 0, stream>>>(
      csum, 512, w1_bf, b1, nullptr, 0, h_bf, 8192, 2048, 512, 16);
  // 12. FFN2 + residual(c) -> osum
  gemm_s<true, false><<<512, 256, 0, stream>>>(
      h_bf, 2048, w2_bf, b2, csum, 512, osum, 8192, 512, 2048, 4);
  // 13. LN3 -> d_out (f32)
  ln_k<<<8192 / 4, 256, 0, stream>>>(osum, g3, beta3, nullptr, out, 8192);
}